// Round 1
// baseline (2859.622 us; speedup 1.0000x reference)
//
#include <hip/hip_runtime.h>
#include <math.h>

#define BB 4
#define TT 4096
#define CC 768
#define HH 64

// ---------------- Kernel 1: QKV projection ----------------
// grid = B*T blocks, 192 threads (3 waves: wave m handles matrix m).
// Stage x row (768 floats) in LDS; thread h computes dot(x_row, W[:,h]).
__global__ __launch_bounds__(192) void qkv_proj(const float* __restrict__ x,
                                                const float* __restrict__ Wq,
                                                const float* __restrict__ Wk,
                                                const float* __restrict__ Wv,
                                                float* __restrict__ qkv) {
    __shared__ float xs[CC];
    const int row = blockIdx.x;                 // b*T + t
    const float* xrow = x + (size_t)row * CC;
    for (int i = threadIdx.x; i < CC; i += 192) xs[i] = xrow[i];
    __syncthreads();

    const int m = threadIdx.x / 64;             // 0=Q,1=K,2=V (wave-uniform)
    const int h = threadIdx.x & 63;
    const float* W = (m == 0) ? Wq : (m == 1) ? Wk : Wv;

    float acc = 0.f;
#pragma unroll 8
    for (int c = 0; c < CC; ++c) {
        acc = fmaf(xs[c], W[c * HH + h], acc);
    }
    // layout: qkv[m][b*T + t][h]
    qkv[((size_t)m * BB * TT + row) * HH + h] = acc;
}

// ---------------- Kernel 2: causal flash attention ----------------
// One wave per query row. Lane d owns head dim d. Keys processed 4 at a
// time with interleaved butterfly reductions; online softmax state m,l,o.
__global__ __launch_bounds__(256) void attn(const float* __restrict__ qkv,
                                            float* __restrict__ out) {
    const float* Q = qkv;
    const float* K = qkv + (size_t)BB * TT * HH;
    const float* V = qkv + 2 * (size_t)BB * TT * HH;

    const int wave = threadIdx.x >> 6;
    const int lane = threadIdx.x & 63;
    const int row  = blockIdx.x * 4 + wave;     // b*T + t
    const int b    = row >> 12;                 // / T
    const int t    = row & (TT - 1);            // % T

    const float* Kb = K + (size_t)b * TT * HH;
    const float* Vb = V + (size_t)b * TT * HH;

    const float qv = Q[(size_t)row * HH + lane] * 0.125f;  // 1/sqrt(64)

    float m = -INFINITY, l = 0.f, o = 0.f;

    for (int j = 0; j <= t; j += 4) {
        float s[4], vv[4];
#pragma unroll
        for (int i = 0; i < 4; ++i) {
            const int jj = j + i;
            const bool ok = (jj <= t);
            const float kk = ok ? Kb[(size_t)jj * HH + lane] : 0.f;
            vv[i] = ok ? Vb[(size_t)jj * HH + lane] : 0.f;
            s[i] = qv * kk;
        }
        // 4 interleaved 64-lane butterfly reductions
#pragma unroll
        for (int msk = 32; msk >= 1; msk >>= 1) {
#pragma unroll
            for (int i = 0; i < 4; ++i) s[i] += __shfl_xor(s[i], msk, 64);
        }
#pragma unroll
        for (int i = 0; i < 4; ++i) {
            if (j + i > t) s[i] = -INFINITY;
        }
        float nm = m;
#pragma unroll
        for (int i = 0; i < 4; ++i) nm = fmaxf(nm, s[i]);
        const float alpha = __expf(m - nm);     // exp(-inf)=0 on first chunk
        l *= alpha;
        o *= alpha;
#pragma unroll
        for (int i = 0; i < 4; ++i) {
            const float p = __expf(s[i] - nm);  // 0 for masked (-inf) keys
            l += p;
            o = fmaf(p, vv[i], o);
        }
        m = nm;
    }

    out[(size_t)row * HH + lane] = o / l;       // l >= exp(0 centered diag) > 0
}

extern "C" void kernel_launch(void* const* d_in, const int* in_sizes, int n_in,
                              void* d_out, int out_size, void* d_ws, size_t ws_size,
                              hipStream_t stream) {
    const float* x  = (const float*)d_in[0];
    const float* Wq = (const float*)d_in[1];
    const float* Wk = (const float*)d_in[2];
    const float* Wv = (const float*)d_in[3];
    float* qkv = (float*)d_ws;                  // 3 * B*T*H floats = 12.6 MB
    float* out = (float*)d_out;

    qkv_proj<<<BB * TT, 192, 0, stream>>>(x, Wq, Wk, Wv, qkv);
    attn<<<(BB * TT) / 4, 256, 0, stream>>>(qkv, out);
}

// Round 2
// 469.842 us; speedup vs baseline: 6.0863x; 6.0863x over previous
//
#include <hip/hip_runtime.h>
#include <math.h>

#define BB 4
#define TT 4096
#define CC 768
#define HH 64
#define LDP 72   // padded LDS row stride in bf16 elems (144 B, 16B-aligned)

typedef __bf16 bf16x8 __attribute__((ext_vector_type(8)));
typedef float floatx4 __attribute__((ext_vector_type(4)));
typedef unsigned short u16x8 __attribute__((ext_vector_type(8)));

__device__ inline unsigned short f2bf(float f) {
    union { float f; unsigned int u; } v; v.f = f;
    unsigned int u = v.u;
    return (unsigned short)((u + 0x7fffu + ((u >> 16) & 1u)) >> 16);
}

// ---------------- Kernel 1: QKV projection (fp32 math, bf16 outputs) --------
// grid = B*T blocks, 192 threads (wave m handles matrix m). V written
// TRANSPOSED (vbt[b][h][t]) so attention can stage V^T without a scatter.
__global__ __launch_bounds__(192) void qkv_proj(const float* __restrict__ x,
                                                const float* __restrict__ Wq,
                                                const float* __restrict__ Wk,
                                                const float* __restrict__ Wv,
                                                unsigned short* __restrict__ qb,
                                                unsigned short* __restrict__ kb,
                                                unsigned short* __restrict__ vbt) {
    __shared__ float xs[CC];
    const int row = blockIdx.x;                 // b*T + t
    const float* xrow = x + (size_t)row * CC;
    for (int i = threadIdx.x; i < CC; i += 192) xs[i] = xrow[i];
    __syncthreads();

    const int m = threadIdx.x / 64;             // 0=Q,1=K,2=V (wave-uniform)
    const int h = threadIdx.x & 63;
    const float* W = (m == 0) ? Wq : (m == 1) ? Wk : Wv;

    float acc = 0.f;
#pragma unroll 8
    for (int c = 0; c < CC; ++c) acc = fmaf(xs[c], W[c * HH + h], acc);

    const int b = row >> 12, t = row & (TT - 1);
    if (m == 0)      qb[(size_t)row * HH + h] = f2bf(acc);
    else if (m == 1) kb[(size_t)row * HH + h] = f2bf(acc);
    else             vbt[((size_t)b * HH + h) * TT + t] = f2bf(acc);
}

// ---------------- Kernel 2: flash attention, MFMA bf16 ----------------------
// One block per 64-query tile (grid = B * T/64 = 256). 4 waves; wave w owns
// query rows [16w,16w+16). Iterate 64-key tiles with online softmax.
// MFMA 16x16x32 bf16. A-layout: lane holds A[m=lane&15][k=quad*8+j].
// C/D-layout: col=lane&15, row=quad*4+reg.
__global__ __launch_bounds__(256) void attn(const unsigned short* __restrict__ qb,
                                            const unsigned short* __restrict__ kb,
                                            const unsigned short* __restrict__ vbt,
                                            float* __restrict__ out) {
    __shared__ unsigned short Ks[64 * LDP];     // K tile  [key][dim]
    __shared__ unsigned short VTs[64 * LDP];    // V^T tile [dim][key]
    __shared__ unsigned short Ps[4][16 * LDP];  // per-wave P [q_local][key]

    const int b   = blockIdx.x >> 6;
    const int qt  = blockIdx.x & 63;
    const int q0  = qt * 64;
    const int tid = threadIdx.x;
    const int w = tid >> 6, lane = tid & 63;
    const int l15 = lane & 15, quad = lane >> 4;

    const unsigned short* Qb  = qb  + (size_t)b * TT * HH;
    const unsigned short* Kb  = kb  + (size_t)b * TT * HH;
    const unsigned short* VTb = vbt + (size_t)b * HH * TT;

    // Q fragments for this wave's 16 rows (persistent in registers)
    const int qrow = q0 + 16 * w + l15;
    const bf16x8 qf0 = *(const bf16x8*)(Qb + (size_t)qrow * HH + quad * 8);
    const bf16x8 qf1 = *(const bf16x8*)(Qb + (size_t)qrow * HH + 32 + quad * 8);

    floatx4 O[4] = {};                          // O[d-group][reg]
    float m_r[4], l_r[4];
#pragma unroll
    for (int r = 0; r < 4; ++r) { m_r[r] = -INFINITY; l_r[r] = 0.f; }

    const int nkt = qt + 1;
    for (int kt = 0; kt < nkt; ++kt) {
        __syncthreads();
        // stage K tile (row-major) and V^T tile (row-major from vbt)
        const unsigned short* Kt = Kb + (size_t)(kt * 64) * HH;
        const unsigned short* Vt = VTb + kt * 64;
#pragma unroll
        for (int e = 0; e < 2; ++e) {
            const int chunk = tid + 256 * e;    // 0..511 -> 64 rows x 8 chunks
            const int r = chunk >> 3, c0 = (chunk & 7) * 8;
            *(u16x8*)(Ks + r * LDP + c0)  = *(const u16x8*)(Kt + r * HH + c0);
            *(u16x8*)(VTs + r * LDP + c0) = *(const u16x8*)(Vt + (size_t)r * TT + c0);
        }
        __syncthreads();

        // S = (Q K^T) * scale : 4 subtiles of 16x16 over the 64 keys
        floatx4 s[4];
#pragma unroll
        for (int ki = 0; ki < 4; ++ki) {
            const bf16x8 kf0 = *(const bf16x8*)(Ks + (16 * ki + l15) * LDP + quad * 8);
            const bf16x8 kf1 = *(const bf16x8*)(Ks + (16 * ki + l15) * LDP + 32 + quad * 8);
            floatx4 c = {};
            c = __builtin_amdgcn_mfma_f32_16x16x32_bf16(qf0, kf0, c, 0, 0, 0);
            c = __builtin_amdgcn_mfma_f32_16x16x32_bf16(qf1, kf1, c, 0, 0, 0);
            s[ki] = c * 0.125f;                 // 1/sqrt(64)
        }

        // causal mask on the diagonal tile (kt == qt): local k <= local q
        if (kt == qt) {
#pragma unroll
            for (int ki = 0; ki < 4; ++ki)
#pragma unroll
                for (int r = 0; r < 4; ++r) {
                    const int kloc = 16 * ki + l15;
                    const int qloc = 16 * w + quad * 4 + r;
                    if (kloc > qloc) s[ki][r] = -INFINITY;
                }
        }

        // online softmax (rows live in reg index r; 16 lanes/quad share rows)
        float mx[4], alpha[4], rs[4];
#pragma unroll
        for (int r = 0; r < 4; ++r) {
            float v = fmaxf(fmaxf(s[0][r], s[1][r]), fmaxf(s[2][r], s[3][r]));
#pragma unroll
            for (int msk = 8; msk >= 1; msk >>= 1) v = fmaxf(v, __shfl_xor(v, msk, 64));
            mx[r] = fmaxf(v, m_r[r]);
            alpha[r] = __expf(m_r[r] - mx[r]);
            rs[r] = 0.f;
        }
#pragma unroll
        for (int ki = 0; ki < 4; ++ki)
#pragma unroll
            for (int r = 0; r < 4; ++r) {
                const float p = __expf(s[ki][r] - mx[r]);
                s[ki][r] = p;
                rs[r] += p;
            }
#pragma unroll
        for (int r = 0; r < 4; ++r) {
            float v = rs[r];
#pragma unroll
            for (int msk = 8; msk >= 1; msk >>= 1) v += __shfl_xor(v, msk, 64);
            l_r[r] = l_r[r] * alpha[r] + v;
            m_r[r] = mx[r];
        }
#pragma unroll
        for (int di = 0; di < 4; ++di)
#pragma unroll
            for (int r = 0; r < 4; ++r) O[di][r] *= alpha[r];

        // P: C-layout -> LDS (bf16), per-wave buffer (no cross-wave barrier)
        unsigned short* Pw = Ps[w];
#pragma unroll
        for (int ki = 0; ki < 4; ++ki)
#pragma unroll
            for (int r = 0; r < 4; ++r)
                Pw[(quad * 4 + r) * LDP + 16 * ki + l15] = f2bf(s[ki][r]);

        // PV: O += P * V  (A = P from LDS in A-layout, B = V^T rows)
        const bf16x8 pf0 = *(const bf16x8*)(Pw + l15 * LDP + quad * 8);
        const bf16x8 pf1 = *(const bf16x8*)(Pw + l15 * LDP + 32 + quad * 8);
#pragma unroll
        for (int di = 0; di < 4; ++di) {
            const bf16x8 vf0 = *(const bf16x8*)(VTs + (16 * di + l15) * LDP + quad * 8);
            const bf16x8 vf1 = *(const bf16x8*)(VTs + (16 * di + l15) * LDP + 32 + quad * 8);
            O[di] = __builtin_amdgcn_mfma_f32_16x16x32_bf16(pf0, vf0, O[di], 0, 0, 0);
            O[di] = __builtin_amdgcn_mfma_f32_16x16x32_bf16(pf1, vf1, O[di], 0, 0, 0);
        }
    }

    // epilogue: out[q][d] = O/l, coalesced per quad-row
    float* outp = out + ((size_t)b * TT + q0 + 16 * w) * HH;
#pragma unroll
    for (int di = 0; di < 4; ++di)
#pragma unroll
        for (int r = 0; r < 4; ++r)
            outp[(quad * 4 + r) * HH + 16 * di + l15] = O[di][r] / l_r[r];
}

extern "C" void kernel_launch(void* const* d_in, const int* in_sizes, int n_in,
                              void* d_out, int out_size, void* d_ws, size_t ws_size,
                              hipStream_t stream) {
    const float* x  = (const float*)d_in[0];
    const float* Wq = (const float*)d_in[1];
    const float* Wk = (const float*)d_in[2];
    const float* Wv = (const float*)d_in[3];
    float* out = (float*)d_out;

    unsigned short* qb  = (unsigned short*)d_ws;            // 2 MB each
    unsigned short* kb  = qb + (size_t)BB * TT * HH;
    unsigned short* vbt = kb + (size_t)BB * TT * HH;

    qkv_proj<<<BB * TT, 192, 0, stream>>>(x, Wq, Wk, Wv, qb, kb, vbt);
    attn<<<BB * (TT / 64), 256, 0, stream>>>(qb, kb, vbt, out);
}

// Round 3
// 253.084 us; speedup vs baseline: 11.2991x; 1.8565x over previous
//
#include <hip/hip_runtime.h>
#include <math.h>

#define BB 4
#define TT 4096
#define CC 768
#define HH 64
#define NN 192   // 3*HH output cols of fused QKV GEMM
#define LDP 72   // padded LDS row stride in bf16 elems

typedef __bf16 bf16x8 __attribute__((ext_vector_type(8)));
typedef float floatx4 __attribute__((ext_vector_type(4)));
typedef unsigned short u16x8 __attribute__((ext_vector_type(8)));

__device__ inline unsigned short f2bf(float f) {
    union { float f; unsigned int u; } v; v.f = f;
    unsigned int u = v.u;
    return (unsigned short)((u + 0x7fffu + ((u >> 16) & 1u)) >> 16);
}

// ---------------- Kernel 0: W prep — concat+transpose+bf16 ------------------
// wt[n][c], n in [0,192): 0-63 Wq cols, 64-127 Wk, 128-191 Wv.
__global__ __launch_bounds__(256) void wprep(const float* __restrict__ Wq,
                                             const float* __restrict__ Wk,
                                             const float* __restrict__ Wv,
                                             unsigned short* __restrict__ wt) {
    const int idx = blockIdx.x * 256 + threadIdx.x;   // n*768 + c
    if (idx >= NN * CC) return;
    const int n = idx / CC, c = idx - n * CC;
    const float* W = (n < 64) ? Wq : (n < 128) ? Wk : Wv;
    wt[idx] = f2bf(W[c * HH + (n & 63)]);
}

// ---------------- Kernel 1: fused QKV projection as MFMA GEMM ---------------
// C[16384 x 192] = X[16384 x 768] * Wt^T. 256 blocks x 4 waves; wave owns
// 16 rows x 192 cols (12 MFMA col-tiles), K-loop 24 x BK=32. No LDS:
// A-frag = 2 float4 from x (cvt to bf16), B-frag = 16B load from Wt row.
__global__ __launch_bounds__(256) void qkv_gemm(const float* __restrict__ x,
                                                const unsigned short* __restrict__ wt,
                                                unsigned short* __restrict__ qb,
                                                unsigned short* __restrict__ kb,
                                                unsigned short* __restrict__ vbt) {
    const int w = threadIdx.x >> 6, lane = threadIdx.x & 63;
    const int l15 = lane & 15, quad = lane >> 4;
    const int m0 = blockIdx.x * 64 + w * 16;          // first of 16 rows

    floatx4 acc[12] = {};

    const float* xrow = x + (size_t)(m0 + l15) * CC + quad * 8;
#pragma unroll 4
    for (int kt = 0; kt < CC / 32; ++kt) {
        const int k0 = kt * 32;
        const float4 a0 = *(const float4*)(xrow + k0);
        const float4 a1 = *(const float4*)(xrow + k0 + 4);
        bf16x8 af;
        af[0] = (__bf16)a0.x; af[1] = (__bf16)a0.y;
        af[2] = (__bf16)a0.z; af[3] = (__bf16)a0.w;
        af[4] = (__bf16)a1.x; af[5] = (__bf16)a1.y;
        af[6] = (__bf16)a1.z; af[7] = (__bf16)a1.w;
#pragma unroll
        for (int n = 0; n < 12; ++n) {
            const bf16x8 bf = *(const bf16x8*)(wt + (size_t)(n * 16 + l15) * CC + k0 + quad * 8);
            acc[n] = __builtin_amdgcn_mfma_f32_16x16x32_bf16(af, bf, acc[n], 0, 0, 0);
        }
    }

    // epilogue. tile row = m0 + quad*4 + r (the t dim), tile col = n*16+l15.
    const int b = m0 >> 12, t0 = (m0 & (TT - 1)) + quad * 4;
#pragma unroll
    for (int n = 0; n < 4; ++n)       // Q: qb[row][h]
#pragma unroll
        for (int r = 0; r < 4; ++r)
            qb[(size_t)(m0 + quad * 4 + r) * HH + n * 16 + l15] = f2bf(acc[n][r]);
#pragma unroll
    for (int n = 0; n < 4; ++n)       // K: kb[row][h]
#pragma unroll
        for (int r = 0; r < 4; ++r)
            kb[(size_t)(m0 + quad * 4 + r) * HH + n * 16 + l15] = f2bf(acc[4 + n][r]);
#pragma unroll
    for (int n = 0; n < 4; ++n) {     // V: vbt[b][h][t], 4 contiguous t -> 8B store
        const int h = n * 16 + l15;
        ushort4 pk;
        pk.x = f2bf(acc[8 + n][0]); pk.y = f2bf(acc[8 + n][1]);
        pk.z = f2bf(acc[8 + n][2]); pk.w = f2bf(acc[8 + n][3]);
        *(ushort4*)(vbt + ((size_t)b * HH + h) * TT + t0) = pk;
    }
}

// ---------------- Kernel 2: flash attention, MFMA bf16 ----------------------
__global__ __launch_bounds__(256) void attn(const unsigned short* __restrict__ qb,
                                            const unsigned short* __restrict__ kb,
                                            const unsigned short* __restrict__ vbt,
                                            float* __restrict__ out) {
    __shared__ unsigned short Ks[64 * LDP];     // K tile  [key][dim]
    __shared__ unsigned short VTs[64 * LDP];    // V^T tile [dim][key]
    __shared__ unsigned short Ps[4][16 * LDP];  // per-wave P [q_local][key]

    const int b   = blockIdx.x >> 6;
    const int qt  = blockIdx.x & 63;
    const int q0  = qt * 64;
    const int tid = threadIdx.x;
    const int w = tid >> 6, lane = tid & 63;
    const int l15 = lane & 15, quad = lane >> 4;

    const unsigned short* Qb  = qb  + (size_t)b * TT * HH;
    const unsigned short* Kb  = kb  + (size_t)b * TT * HH;
    const unsigned short* VTb = vbt + (size_t)b * HH * TT;

    const int qrow = q0 + 16 * w + l15;
    const bf16x8 qf0 = *(const bf16x8*)(Qb + (size_t)qrow * HH + quad * 8);
    const bf16x8 qf1 = *(const bf16x8*)(Qb + (size_t)qrow * HH + 32 + quad * 8);

    floatx4 O[4] = {};
    float m_r[4], l_r[4];
#pragma unroll
    for (int r = 0; r < 4; ++r) { m_r[r] = -INFINITY; l_r[r] = 0.f; }

    const int nkt = qt + 1;
    for (int kt = 0; kt < nkt; ++kt) {
        __syncthreads();
        const unsigned short* Kt = Kb + (size_t)(kt * 64) * HH;
        const unsigned short* Vt = VTb + kt * 64;
#pragma unroll
        for (int e = 0; e < 2; ++e) {
            const int chunk = tid + 256 * e;
            const int r = chunk >> 3, c0 = (chunk & 7) * 8;
            *(u16x8*)(Ks + r * LDP + c0)  = *(const u16x8*)(Kt + r * HH + c0);
            *(u16x8*)(VTs + r * LDP + c0) = *(const u16x8*)(Vt + (size_t)r * TT + c0);
        }
        __syncthreads();

        floatx4 s[4];
#pragma unroll
        for (int ki = 0; ki < 4; ++ki) {
            const bf16x8 kf0 = *(const bf16x8*)(Ks + (16 * ki + l15) * LDP + quad * 8);
            const bf16x8 kf1 = *(const bf16x8*)(Ks + (16 * ki + l15) * LDP + 32 + quad * 8);
            floatx4 c = {};
            c = __builtin_amdgcn_mfma_f32_16x16x32_bf16(qf0, kf0, c, 0, 0, 0);
            c = __builtin_amdgcn_mfma_f32_16x16x32_bf16(qf1, kf1, c, 0, 0, 0);
            s[ki] = c * 0.125f;
        }

        if (kt == qt) {
#pragma unroll
            for (int ki = 0; ki < 4; ++ki)
#pragma unroll
                for (int r = 0; r < 4; ++r) {
                    const int kloc = 16 * ki + l15;
                    const int qloc = 16 * w + quad * 4 + r;
                    if (kloc > qloc) s[ki][r] = -INFINITY;
                }
        }

        float mx[4], alpha[4], rs[4];
#pragma unroll
        for (int r = 0; r < 4; ++r) {
            float v = fmaxf(fmaxf(s[0][r], s[1][r]), fmaxf(s[2][r], s[3][r]));
#pragma unroll
            for (int msk = 8; msk >= 1; msk >>= 1) v = fmaxf(v, __shfl_xor(v, msk, 64));
            mx[r] = fmaxf(v, m_r[r]);
            alpha[r] = __expf(m_r[r] - mx[r]);
            rs[r] = 0.f;
        }
#pragma unroll
        for (int ki = 0; ki < 4; ++ki)
#pragma unroll
            for (int r = 0; r < 4; ++r) {
                const float p = __expf(s[ki][r] - mx[r]);
                s[ki][r] = p;
                rs[r] += p;
            }
#pragma unroll
        for (int r = 0; r < 4; ++r) {
            float v = rs[r];
#pragma unroll
            for (int msk = 8; msk >= 1; msk >>= 1) v += __shfl_xor(v, msk, 64);
            l_r[r] = l_r[r] * alpha[r] + v;
            m_r[r] = mx[r];
        }
#pragma unroll
        for (int di = 0; di < 4; ++di)
#pragma unroll
            for (int r = 0; r < 4; ++r) O[di][r] *= alpha[r];

        unsigned short* Pw = Ps[w];
#pragma unroll
        for (int ki = 0; ki < 4; ++ki)
#pragma unroll
            for (int r = 0; r < 4; ++r)
                Pw[(quad * 4 + r) * LDP + 16 * ki + l15] = f2bf(s[ki][r]);

        const bf16x8 pf0 = *(const bf16x8*)(Pw + l15 * LDP + quad * 8);
        const bf16x8 pf1 = *(const bf16x8*)(Pw + l15 * LDP + 32 + quad * 8);
#pragma unroll
        for (int di = 0; di < 4; ++di) {
            const bf16x8 vf0 = *(const bf16x8*)(VTs + (16 * di + l15) * LDP + quad * 8);
            const bf16x8 vf1 = *(const bf16x8*)(VTs + (16 * di + l15) * LDP + 32 + quad * 8);
            O[di] = __builtin_amdgcn_mfma_f32_16x16x32_bf16(pf0, vf0, O[di], 0, 0, 0);
            O[di] = __builtin_amdgcn_mfma_f32_16x16x32_bf16(pf1, vf1, O[di], 0, 0, 0);
        }
    }

    float* outp = out + ((size_t)b * TT + q0 + 16 * w) * HH;
#pragma unroll
    for (int di = 0; di < 4; ++di)
#pragma unroll
        for (int r = 0; r < 4; ++r)
            outp[(quad * 4 + r) * HH + 16 * di + l15] = O[di][r] / l_r[r];
}

extern "C" void kernel_launch(void* const* d_in, const int* in_sizes, int n_in,
                              void* d_out, int out_size, void* d_ws, size_t ws_size,
                              hipStream_t stream) {
    const float* x  = (const float*)d_in[0];
    const float* Wq = (const float*)d_in[1];
    const float* Wk = (const float*)d_in[2];
    const float* Wv = (const float*)d_in[3];
    float* out = (float*)d_out;

    unsigned short* qb  = (unsigned short*)d_ws;            // 2 MB each
    unsigned short* kb  = qb + (size_t)BB * TT * HH;
    unsigned short* vbt = kb + (size_t)BB * TT * HH;
    unsigned short* wt  = vbt + (size_t)BB * TT * HH;       // 288 KB

    wprep<<<(NN * CC + 255) / 256, 256, 0, stream>>>(Wq, Wk, Wv, wt);
    qkv_gemm<<<(BB * TT) / 64, 256, 0, stream>>>(x, wt, qb, kb, vbt);
    attn<<<BB * (TT / 64), 256, 0, stream>>>(qb, kb, vbt, out);
}

// Round 4
// 207.196 us; speedup vs baseline: 13.8015x; 1.2215x over previous
//
#include <hip/hip_runtime.h>
#include <math.h>

#define BB 4
#define TT 4096
#define CC 768
#define HH 64
#define NN 192   // 3*HH output cols of fused QKV GEMM
#define LDP 72   // padded LDS row stride in bf16 elems

typedef __bf16 bf16x8 __attribute__((ext_vector_type(8)));
typedef float floatx4 __attribute__((ext_vector_type(4)));
typedef unsigned short u16x8 __attribute__((ext_vector_type(8)));

__device__ inline unsigned short f2bf(float f) {
    union { __bf16 b; unsigned short u; } v;
    v.b = (__bf16)f;                      // hw cvt (RTNE) on gfx950
    return v.u;
}

// ---------------- Kernel 0: W prep — concat+transpose+bf16 ------------------
__global__ __launch_bounds__(256) void wprep(const float* __restrict__ Wq,
                                             const float* __restrict__ Wk,
                                             const float* __restrict__ Wv,
                                             unsigned short* __restrict__ wt) {
    const int idx = blockIdx.x * 256 + threadIdx.x;   // n*768 + c
    if (idx >= NN * CC) return;
    const int n = idx / CC, c = idx - n * CC;
    const float* W = (n < 64) ? Wq : (n < 128) ? Wk : Wv;
    wt[idx] = f2bf(W[c * HH + (n & 63)]);
}

// ---------------- Kernel 1: fused QKV projection as MFMA GEMM ---------------
// 512 blocks x 128 threads (2 waves); wave owns 16 rows x 192 cols.
// 2 blocks/CU co-resident to hide L2 latency of B-fragment loads.
__global__ __launch_bounds__(128) void qkv_gemm(const float* __restrict__ x,
                                                const unsigned short* __restrict__ wt,
                                                unsigned short* __restrict__ qb,
                                                unsigned short* __restrict__ kb,
                                                unsigned short* __restrict__ vbt) {
    const int w = threadIdx.x >> 6, lane = threadIdx.x & 63;
    const int l15 = lane & 15, quad = lane >> 4;
    const int m0 = blockIdx.x * 32 + w * 16;          // first of 16 rows

    floatx4 acc[12] = {};

    const float* xrow = x + (size_t)(m0 + l15) * CC + quad * 8;
#pragma unroll 4
    for (int kt = 0; kt < CC / 32; ++kt) {
        const int k0 = kt * 32;
        const float4 a0 = *(const float4*)(xrow + k0);
        const float4 a1 = *(const float4*)(xrow + k0 + 4);
        bf16x8 af;
        af[0] = (__bf16)a0.x; af[1] = (__bf16)a0.y;
        af[2] = (__bf16)a0.z; af[3] = (__bf16)a0.w;
        af[4] = (__bf16)a1.x; af[5] = (__bf16)a1.y;
        af[6] = (__bf16)a1.z; af[7] = (__bf16)a1.w;
#pragma unroll
        for (int n = 0; n < 12; ++n) {
            const bf16x8 bf = *(const bf16x8*)(wt + (size_t)(n * 16 + l15) * CC + k0 + quad * 8);
            acc[n] = __builtin_amdgcn_mfma_f32_16x16x32_bf16(af, bf, acc[n], 0, 0, 0);
        }
    }

    const int b = m0 >> 12, t0 = (m0 & (TT - 1)) + quad * 4;
#pragma unroll
    for (int n = 0; n < 4; ++n)
#pragma unroll
        for (int r = 0; r < 4; ++r)
            qb[(size_t)(m0 + quad * 4 + r) * HH + n * 16 + l15] = f2bf(acc[n][r]);
#pragma unroll
    for (int n = 0; n < 4; ++n)
#pragma unroll
        for (int r = 0; r < 4; ++r)
            kb[(size_t)(m0 + quad * 4 + r) * HH + n * 16 + l15] = f2bf(acc[4 + n][r]);
#pragma unroll
    for (int n = 0; n < 4; ++n) {
        const int h = n * 16 + l15;
        ushort4 pk;
        pk.x = f2bf(acc[8 + n][0]); pk.y = f2bf(acc[8 + n][1]);
        pk.z = f2bf(acc[8 + n][2]); pk.w = f2bf(acc[8 + n][3]);
        *(ushort4*)(vbt + ((size_t)b * HH + h) * TT + t0) = pk;
    }
}

// ------------- Kernel 2a: flash attention phase 1 (split-K partials) --------
// grid = BB * 160. Each block: one 64-query tile x one chunk of <=16 key
// tiles. Writes unnormalized partial O (fp32) + per-row (m,l).
__global__ __launch_bounds__(256) void attn_part(const unsigned short* __restrict__ qb,
                                                 const unsigned short* __restrict__ kb,
                                                 const unsigned short* __restrict__ vbt,
                                                 float* __restrict__ Opart,
                                                 float* __restrict__ ml) {
    __shared__ unsigned short Ks[64 * LDP];
    __shared__ unsigned short VTs[64 * LDP];
    __shared__ unsigned short Ps[4][16 * LDP];

    const int b   = blockIdx.x / 160;
    const int rem = blockIdx.x - b * 160;
    int qt, ch;
    if (rem < 16)      { qt = rem;               ch = 0; }
    else if (rem < 48) { qt = 16 + (rem - 16) / 2; ch = (rem - 16) % 2; }
    else if (rem < 96) { qt = 32 + (rem - 48) / 3; ch = (rem - 48) % 3; }
    else               { qt = 48 + (rem - 96) / 4; ch = (rem - 96) % 4; }

    const int q0  = qt * 64;
    const int tid = threadIdx.x;
    const int w = tid >> 6, lane = tid & 63;
    const int l15 = lane & 15, quad = lane >> 4;

    const unsigned short* Qb  = qb  + (size_t)b * TT * HH;
    const unsigned short* Kb  = kb  + (size_t)b * TT * HH;
    const unsigned short* VTb = vbt + (size_t)b * HH * TT;

    const int qrow = q0 + 16 * w + l15;
    const bf16x8 qf0 = *(const bf16x8*)(Qb + (size_t)qrow * HH + quad * 8);
    const bf16x8 qf1 = *(const bf16x8*)(Qb + (size_t)qrow * HH + 32 + quad * 8);

    floatx4 O[4] = {};
    float m_r[4], l_r[4];
#pragma unroll
    for (int r = 0; r < 4; ++r) { m_r[r] = -INFINITY; l_r[r] = 0.f; }

    const int kt0 = ch * 16;
    const int kt1 = min(kt0 + 16, qt + 1);
    for (int kt = kt0; kt < kt1; ++kt) {
        __syncthreads();
        const unsigned short* Kt = Kb + (size_t)(kt * 64) * HH;
        const unsigned short* Vt = VTb + kt * 64;
#pragma unroll
        for (int e = 0; e < 2; ++e) {
            const int chunk = tid + 256 * e;
            const int r = chunk >> 3, c0 = (chunk & 7) * 8;
            *(u16x8*)(Ks + r * LDP + c0)  = *(const u16x8*)(Kt + r * HH + c0);
            *(u16x8*)(VTs + r * LDP + c0) = *(const u16x8*)(Vt + (size_t)r * TT + c0);
        }
        __syncthreads();

        floatx4 s[4];
#pragma unroll
        for (int ki = 0; ki < 4; ++ki) {
            const bf16x8 kf0 = *(const bf16x8*)(Ks + (16 * ki + l15) * LDP + quad * 8);
            const bf16x8 kf1 = *(const bf16x8*)(Ks + (16 * ki + l15) * LDP + 32 + quad * 8);
            floatx4 c = {};
            c = __builtin_amdgcn_mfma_f32_16x16x32_bf16(qf0, kf0, c, 0, 0, 0);
            c = __builtin_amdgcn_mfma_f32_16x16x32_bf16(qf1, kf1, c, 0, 0, 0);
            s[ki] = c * 0.125f;
        }

        if (kt == qt) {
#pragma unroll
            for (int ki = 0; ki < 4; ++ki)
#pragma unroll
                for (int r = 0; r < 4; ++r) {
                    const int kloc = 16 * ki + l15;
                    const int qloc = 16 * w + quad * 4 + r;
                    if (kloc > qloc) s[ki][r] = -INFINITY;
                }
        }

        float mx[4], alpha[4], rs[4];
#pragma unroll
        for (int r = 0; r < 4; ++r) {
            float v = fmaxf(fmaxf(s[0][r], s[1][r]), fmaxf(s[2][r], s[3][r]));
#pragma unroll
            for (int msk = 8; msk >= 1; msk >>= 1) v = fmaxf(v, __shfl_xor(v, msk, 64));
            mx[r] = fmaxf(v, m_r[r]);
            alpha[r] = __expf(m_r[r] - mx[r]);
            rs[r] = 0.f;
        }
#pragma unroll
        for (int ki = 0; ki < 4; ++ki)
#pragma unroll
            for (int r = 0; r < 4; ++r) {
                const float p = __expf(s[ki][r] - mx[r]);
                s[ki][r] = p;
                rs[r] += p;
            }
#pragma unroll
        for (int r = 0; r < 4; ++r) {
            float v = rs[r];
#pragma unroll
            for (int msk = 8; msk >= 1; msk >>= 1) v += __shfl_xor(v, msk, 64);
            l_r[r] = l_r[r] * alpha[r] + v;
            m_r[r] = mx[r];
        }
#pragma unroll
        for (int di = 0; di < 4; ++di)
#pragma unroll
            for (int r = 0; r < 4; ++r) O[di][r] *= alpha[r];

        unsigned short* Pw = Ps[w];
#pragma unroll
        for (int ki = 0; ki < 4; ++ki)
#pragma unroll
            for (int r = 0; r < 4; ++r)
                Pw[(quad * 4 + r) * LDP + 16 * ki + l15] = f2bf(s[ki][r]);

        const bf16x8 pf0 = *(const bf16x8*)(Pw + l15 * LDP + quad * 8);
        const bf16x8 pf1 = *(const bf16x8*)(Pw + l15 * LDP + 32 + quad * 8);
#pragma unroll
        for (int di = 0; di < 4; ++di) {
            const bf16x8 vf0 = *(const bf16x8*)(VTs + (16 * di + l15) * LDP + quad * 8);
            const bf16x8 vf1 = *(const bf16x8*)(VTs + (16 * di + l15) * LDP + 32 + quad * 8);
            O[di] = __builtin_amdgcn_mfma_f32_16x16x32_bf16(pf0, vf0, O[di], 0, 0, 0);
            O[di] = __builtin_amdgcn_mfma_f32_16x16x32_bf16(pf1, vf1, O[di], 0, 0, 0);
        }
    }

    // partial epilogue: unnormalized O + (m,l)
    const int pbase = ((b * 64 + qt) * 4 + ch) * 64;           // partial row base
    float* Op = Opart + (size_t)pbase * HH + 16 * w * HH;
#pragma unroll
    for (int di = 0; di < 4; ++di)
#pragma unroll
        for (int r = 0; r < 4; ++r)
            Op[(quad * 4 + r) * HH + 16 * di + l15] = O[di][r];
    if (l15 == 0) {
#pragma unroll
        for (int r = 0; r < 4; ++r) {
            const int prow = pbase + 16 * w + quad * 4 + r;
            ml[prow * 2]     = m_r[r];
            ml[prow * 2 + 1] = l_r[r];
        }
    }
}

// ------------- Kernel 2b: merge partials --------------------------------
__global__ __launch_bounds__(256) void attn_merge(const float* __restrict__ Opart,
                                                  const float* __restrict__ ml,
                                                  float* __restrict__ out) {
    const int g = blockIdx.x * 256 + threadIdx.x;   // row*64 + d
    const int row = g >> 6, d = g & 63;
    const int b = row >> 12, t = row & (TT - 1);
    const int qt = t >> 6, rloc = t & 63;
    const int nchunk = (qt >> 4) + 1;
    const int pbase = ((b * 64 + qt) * 4) * 64 + rloc;

    float M = -INFINITY;
#pragma unroll 4
    for (int c = 0; c < nchunk; ++c) M = fmaxf(M, ml[(pbase + c * 64) * 2]);
    float O = 0.f, L = 0.f;
#pragma unroll 4
    for (int c = 0; c < nchunk; ++c) {
        const int idx = pbase + c * 64;
        const float wgt = __expf(ml[idx * 2] - M);
        L += wgt * ml[idx * 2 + 1];
        O += wgt * Opart[(size_t)idx * HH + d];
    }
    out[(size_t)row * HH + d] = O / L;
}

// ------------- Fallback: single-pass attention (R3 version) -----------------
__global__ __launch_bounds__(256) void attn_full(const unsigned short* __restrict__ qb,
                                                 const unsigned short* __restrict__ kb,
                                                 const unsigned short* __restrict__ vbt,
                                                 float* __restrict__ out) {
    __shared__ unsigned short Ks[64 * LDP];
    __shared__ unsigned short VTs[64 * LDP];
    __shared__ unsigned short Ps[4][16 * LDP];

    const int b   = blockIdx.x >> 6;
    const int qt  = blockIdx.x & 63;
    const int q0  = qt * 64;
    const int tid = threadIdx.x;
    const int w = tid >> 6, lane = tid & 63;
    const int l15 = lane & 15, quad = lane >> 4;

    const unsigned short* Qb  = qb  + (size_t)b * TT * HH;
    const unsigned short* Kb  = kb  + (size_t)b * TT * HH;
    const unsigned short* VTb = vbt + (size_t)b * HH * TT;

    const int qrow = q0 + 16 * w + l15;
    const bf16x8 qf0 = *(const bf16x8*)(Qb + (size_t)qrow * HH + quad * 8);
    const bf16x8 qf1 = *(const bf16x8*)(Qb + (size_t)qrow * HH + 32 + quad * 8);

    floatx4 O[4] = {};
    float m_r[4], l_r[4];
#pragma unroll
    for (int r = 0; r < 4; ++r) { m_r[r] = -INFINITY; l_r[r] = 0.f; }

    for (int kt = 0; kt <= qt; ++kt) {
        __syncthreads();
        const unsigned short* Kt = Kb + (size_t)(kt * 64) * HH;
        const unsigned short* Vt = VTb + kt * 64;
#pragma unroll
        for (int e = 0; e < 2; ++e) {
            const int chunk = tid + 256 * e;
            const int r = chunk >> 3, c0 = (chunk & 7) * 8;
            *(u16x8*)(Ks + r * LDP + c0)  = *(const u16x8*)(Kt + r * HH + c0);
            *(u16x8*)(VTs + r * LDP + c0) = *(const u16x8*)(Vt + (size_t)r * TT + c0);
        }
        __syncthreads();

        floatx4 s[4];
#pragma unroll
        for (int ki = 0; ki < 4; ++ki) {
            const bf16x8 kf0 = *(const bf16x8*)(Ks + (16 * ki + l15) * LDP + quad * 8);
            const bf16x8 kf1 = *(const bf16x8*)(Ks + (16 * ki + l15) * LDP + 32 + quad * 8);
            floatx4 c = {};
            c = __builtin_amdgcn_mfma_f32_16x16x32_bf16(qf0, kf0, c, 0, 0, 0);
            c = __builtin_amdgcn_mfma_f32_16x16x32_bf16(qf1, kf1, c, 0, 0, 0);
            s[ki] = c * 0.125f;
        }
        if (kt == qt) {
#pragma unroll
            for (int ki = 0; ki < 4; ++ki)
#pragma unroll
                for (int r = 0; r < 4; ++r)
                    if (16 * ki + l15 > 16 * w + quad * 4 + r) s[ki][r] = -INFINITY;
        }
        float mx[4], alpha[4], rs[4];
#pragma unroll
        for (int r = 0; r < 4; ++r) {
            float v = fmaxf(fmaxf(s[0][r], s[1][r]), fmaxf(s[2][r], s[3][r]));
#pragma unroll
            for (int msk = 8; msk >= 1; msk >>= 1) v = fmaxf(v, __shfl_xor(v, msk, 64));
            mx[r] = fmaxf(v, m_r[r]);
            alpha[r] = __expf(m_r[r] - mx[r]);
            rs[r] = 0.f;
        }
#pragma unroll
        for (int ki = 0; ki < 4; ++ki)
#pragma unroll
            for (int r = 0; r < 4; ++r) {
                const float p = __expf(s[ki][r] - mx[r]);
                s[ki][r] = p; rs[r] += p;
            }
#pragma unroll
        for (int r = 0; r < 4; ++r) {
            float v = rs[r];
#pragma unroll
            for (int msk = 8; msk >= 1; msk >>= 1) v += __shfl_xor(v, msk, 64);
            l_r[r] = l_r[r] * alpha[r] + v;
            m_r[r] = mx[r];
        }
#pragma unroll
        for (int di = 0; di < 4; ++di)
#pragma unroll
            for (int r = 0; r < 4; ++r) O[di][r] *= alpha[r];

        unsigned short* Pw = Ps[w];
#pragma unroll
        for (int ki = 0; ki < 4; ++ki)
#pragma unroll
            for (int r = 0; r < 4; ++r)
                Pw[(quad * 4 + r) * LDP + 16 * ki + l15] = f2bf(s[ki][r]);

        const bf16x8 pf0 = *(const bf16x8*)(Pw + l15 * LDP + quad * 8);
        const bf16x8 pf1 = *(const bf16x8*)(Pw + l15 * LDP + 32 + quad * 8);
#pragma unroll
        for (int di = 0; di < 4; ++di) {
            const bf16x8 vf0 = *(const bf16x8*)(VTs + (16 * di + l15) * LDP + quad * 8);
            const bf16x8 vf1 = *(const bf16x8*)(VTs + (16 * di + l15) * LDP + 32 + quad * 8);
            O[di] = __builtin_amdgcn_mfma_f32_16x16x32_bf16(pf0, vf0, O[di], 0, 0, 0);
            O[di] = __builtin_amdgcn_mfma_f32_16x16x32_bf16(pf1, vf1, O[di], 0, 0, 0);
        }
    }
    float* outp = out + ((size_t)b * TT + q0 + 16 * w) * HH;
#pragma unroll
    for (int di = 0; di < 4; ++di)
#pragma unroll
        for (int r = 0; r < 4; ++r)
            outp[(quad * 4 + r) * HH + 16 * di + l15] = O[di][r] / l_r[r];
}

extern "C" void kernel_launch(void* const* d_in, const int* in_sizes, int n_in,
                              void* d_out, int out_size, void* d_ws, size_t ws_size,
                              hipStream_t stream) {
    const float* x  = (const float*)d_in[0];
    const float* Wq = (const float*)d_in[1];
    const float* Wk = (const float*)d_in[2];
    const float* Wv = (const float*)d_in[3];
    float* out = (float*)d_out;

    const size_t nQKV = (size_t)BB * TT * HH;           // 1 Mi elems
    unsigned short* qb  = (unsigned short*)d_ws;
    unsigned short* kb  = qb + nQKV;
    unsigned short* vbt = kb + nQKV;
    unsigned short* wt  = vbt + nQKV;                   // NN*CC ushorts
    char* after_wt = (char*)(wt + (size_t)NN * CC);
    float* Opart = (float*)after_wt;                    // 256*4*64*64 floats = 16 MB
    float* ml    = Opart + (size_t)256 * 4 * 64 * HH;   // 256*4*64*2 floats = 512 KB
    const size_t need = (size_t)((char*)(ml + 256 * 4 * 64 * 2) - (char*)d_ws);

    wprep<<<(NN * CC + 255) / 256, 256, 0, stream>>>(Wq, Wk, Wv, wt);
    qkv_gemm<<<(BB * TT) / 32, 128, 0, stream>>>(x, wt, qb, kb, vbt);
    if (ws_size >= need) {
        attn_part<<<BB * 160, 256, 0, stream>>>(qb, kb, vbt, Opart, ml);
        attn_merge<<<(BB * TT * HH) / 256, 256, 0, stream>>>(Opart, ml, out);
    } else {
        attn_full<<<BB * (TT / 64), 256, 0, stream>>>(qb, kb, vbt, out);
    }
}

// Round 5
// 155.834 us; speedup vs baseline: 18.3505x; 1.3296x over previous
//
#include <hip/hip_runtime.h>
#include <math.h>

#define BB 4
#define TT 4096
#define CC 768
#define HH 64
#define NN 192   // 3*HH output cols of fused QKV GEMM
#define LDP 72   // padded LDS row stride in bf16 elems (144 B -> 2-way bank alias, free)
#define GR 32    // rows per qkv_gemm block
#define BKK 64   // K per staging step

typedef __bf16 bf16x8 __attribute__((ext_vector_type(8)));
typedef float floatx4 __attribute__((ext_vector_type(4)));
typedef unsigned short u16x8 __attribute__((ext_vector_type(8)));

__device__ inline unsigned short f2bf(float f) {
    union { __bf16 b; unsigned short u; } v;
    v.b = (__bf16)f;                      // hw cvt (RTNE) on gfx950
    return v.u;
}

// ---------------- Kernel 0: W prep — concat+transpose+bf16 ------------------
__global__ __launch_bounds__(256) void wprep(const float* __restrict__ Wq,
                                             const float* __restrict__ Wk,
                                             const float* __restrict__ Wv,
                                             unsigned short* __restrict__ wt) {
    const int idx = blockIdx.x * 256 + threadIdx.x;   // n*768 + c
    if (idx >= NN * CC) return;
    const int n = idx / CC, c = idx - n * CC;
    const float* W = (n < 64) ? Wq : (n < 128) ? Wk : Wv;
    wt[idx] = f2bf(W[c * HH + (n & 63)]);
}

// ---------------- Kernel 1: fused QKV projection, LDS-staged MFMA GEMM ------
// 512 blocks x 256 threads. Block: 32 rows x 192 cols. Wave w: rows
// 16*(w&1).., cols 96*(w>>1).. (6 col-tiles). K-loop: 12 steps of BK=64 with
// coalesced staging of A (x, fp32->bf16) and B (wt) into padded LDS.
__global__ __launch_bounds__(256) void qkv_gemm(const float* __restrict__ x,
                                                const unsigned short* __restrict__ wt,
                                                unsigned short* __restrict__ qb,
                                                unsigned short* __restrict__ kb,
                                                unsigned short* __restrict__ vbt) {
    __shared__ unsigned short As[GR * LDP];   //  4.6 KB
    __shared__ unsigned short Bs[NN * LDP];   // 27.6 KB

    const int tid = threadIdx.x;
    const int w = tid >> 6, lane = tid & 63;
    const int l15 = lane & 15, quad = lane >> 4;
    const int m0 = blockIdx.x * GR;
    const int r0 = (w & 1) * 16;              // wave row offset in tile
    const int n0 = (w >> 1) * 96;             // wave col offset

    floatx4 acc[6] = {};

    for (int k0 = 0; k0 < CC; k0 += BKK) {
        __syncthreads();
        // stage A: 32 rows x 64 k, fp32 -> bf16. 16 threads/row, coalesced.
#pragma unroll
        for (int e = 0; e < 2; ++e) {
            const int c = tid + 256 * e;          // 0..511
            const int r = c >> 4, c4 = (c & 15) * 4;
            const float4 v = *(const float4*)(x + (size_t)(m0 + r) * CC + k0 + c4);
            ushort4 pk;
            pk.x = f2bf(v.x); pk.y = f2bf(v.y); pk.z = f2bf(v.z); pk.w = f2bf(v.w);
            *(ushort4*)(As + r * LDP + c4) = pk;
        }
        // stage B: 192 rows x 64 k bf16. 8 threads/row, coalesced 16B chunks.
#pragma unroll
        for (int e = 0; e < 6; ++e) {
            const int c = tid + 256 * e;          // 0..1535
            const int r = c >> 3, c8 = (c & 7) * 8;
            *(u16x8*)(Bs + r * LDP + c8) = *(const u16x8*)(wt + (size_t)r * CC + k0 + c8);
        }
        __syncthreads();

        const bf16x8 a0 = *(const bf16x8*)(As + (r0 + l15) * LDP + quad * 8);
        const bf16x8 a1 = *(const bf16x8*)(As + (r0 + l15) * LDP + 32 + quad * 8);
#pragma unroll
        for (int j = 0; j < 6; ++j) {
            const bf16x8 b0 = *(const bf16x8*)(Bs + (n0 + j * 16 + l15) * LDP + quad * 8);
            const bf16x8 b1 = *(const bf16x8*)(Bs + (n0 + j * 16 + l15) * LDP + 32 + quad * 8);
            acc[j] = __builtin_amdgcn_mfma_f32_16x16x32_bf16(a0, b0, acc[j], 0, 0, 0);
            acc[j] = __builtin_amdgcn_mfma_f32_16x16x32_bf16(a1, b1, acc[j], 0, 0, 0);
        }
    }

    // epilogue: global col n = n0+16j+l15; n>>6 uniform per (w,j) since
    // 16-aligned chunks never straddle a 64 boundary.
    const int b = m0 >> 12;
    const int tloc = (m0 & (TT - 1)) + r0 + quad * 4;   // t of reg r=0
#pragma unroll
    for (int j = 0; j < 6; ++j) {
        const int n = n0 + j * 16 + l15;
        const int mid = n >> 6;                  // 0=Q,1=K,2=V
        const int h = n & 63;
        if (mid == 2) {
            ushort4 pk;
            pk.x = f2bf(acc[j][0]); pk.y = f2bf(acc[j][1]);
            pk.z = f2bf(acc[j][2]); pk.w = f2bf(acc[j][3]);
            *(ushort4*)(vbt + ((size_t)b * HH + h) * TT + tloc) = pk;
        } else {
            unsigned short* dst = (mid == 0) ? qb : kb;
#pragma unroll
            for (int r = 0; r < 4; ++r)
                dst[(size_t)(m0 + r0 + quad * 4 + r) * HH + h] = f2bf(acc[j][r]);
        }
    }
}

// ------------- Kernel 2a: flash attention phase 1 (split-K partials) --------
// grid = BB * 160. Each block: one 64-query tile x one chunk of <=16 key
// tiles. Writes unnormalized partial O (fp32) + per-row (m,l).
__global__ __launch_bounds__(256) void attn_part(const unsigned short* __restrict__ qb,
                                                 const unsigned short* __restrict__ kb,
                                                 const unsigned short* __restrict__ vbt,
                                                 float* __restrict__ Opart,
                                                 float* __restrict__ ml) {
    __shared__ unsigned short Ks[64 * LDP];
    __shared__ unsigned short VTs[64 * LDP];
    __shared__ unsigned short Ps[4][16 * LDP];

    const int b   = blockIdx.x / 160;
    const int rem = blockIdx.x - b * 160;
    int qt, ch;
    if (rem < 16)      { qt = rem;               ch = 0; }
    else if (rem < 48) { qt = 16 + (rem - 16) / 2; ch = (rem - 16) % 2; }
    else if (rem < 96) { qt = 32 + (rem - 48) / 3; ch = (rem - 48) % 3; }
    else               { qt = 48 + (rem - 96) / 4; ch = (rem - 96) % 4; }

    const int q0  = qt * 64;
    const int tid = threadIdx.x;
    const int w = tid >> 6, lane = tid & 63;
    const int l15 = lane & 15, quad = lane >> 4;

    const unsigned short* Qb  = qb  + (size_t)b * TT * HH;
    const unsigned short* Kb  = kb  + (size_t)b * TT * HH;
    const unsigned short* VTb = vbt + (size_t)b * HH * TT;

    const int qrow = q0 + 16 * w + l15;
    const bf16x8 qf0 = *(const bf16x8*)(Qb + (size_t)qrow * HH + quad * 8);
    const bf16x8 qf1 = *(const bf16x8*)(Qb + (size_t)qrow * HH + 32 + quad * 8);

    floatx4 O[4] = {};
    float m_r[4], l_r[4];
#pragma unroll
    for (int r = 0; r < 4; ++r) { m_r[r] = -INFINITY; l_r[r] = 0.f; }

    const int kt0 = ch * 16;
    const int kt1 = min(kt0 + 16, qt + 1);
    for (int kt = kt0; kt < kt1; ++kt) {
        __syncthreads();
        const unsigned short* Kt = Kb + (size_t)(kt * 64) * HH;
        const unsigned short* Vt = VTb + kt * 64;
#pragma unroll
        for (int e = 0; e < 2; ++e) {
            const int chunk = tid + 256 * e;
            const int r = chunk >> 3, c0 = (chunk & 7) * 8;
            *(u16x8*)(Ks + r * LDP + c0)  = *(const u16x8*)(Kt + r * HH + c0);
            *(u16x8*)(VTs + r * LDP + c0) = *(const u16x8*)(Vt + (size_t)r * TT + c0);
        }
        __syncthreads();

        floatx4 s[4];
#pragma unroll
        for (int ki = 0; ki < 4; ++ki) {
            const bf16x8 kf0 = *(const bf16x8*)(Ks + (16 * ki + l15) * LDP + quad * 8);
            const bf16x8 kf1 = *(const bf16x8*)(Ks + (16 * ki + l15) * LDP + 32 + quad * 8);
            floatx4 c = {};
            c = __builtin_amdgcn_mfma_f32_16x16x32_bf16(qf0, kf0, c, 0, 0, 0);
            c = __builtin_amdgcn_mfma_f32_16x16x32_bf16(qf1, kf1, c, 0, 0, 0);
            s[ki] = c * 0.125f;
        }

        if (kt == qt) {
#pragma unroll
            for (int ki = 0; ki < 4; ++ki)
#pragma unroll
                for (int r = 0; r < 4; ++r) {
                    const int kloc = 16 * ki + l15;
                    const int qloc = 16 * w + quad * 4 + r;
                    if (kloc > qloc) s[ki][r] = -INFINITY;
                }
        }

        float mx[4], alpha[4], rs[4];
#pragma unroll
        for (int r = 0; r < 4; ++r) {
            float v = fmaxf(fmaxf(s[0][r], s[1][r]), fmaxf(s[2][r], s[3][r]));
#pragma unroll
            for (int msk = 8; msk >= 1; msk >>= 1) v = fmaxf(v, __shfl_xor(v, msk, 64));
            mx[r] = fmaxf(v, m_r[r]);
            alpha[r] = __expf(m_r[r] - mx[r]);
            rs[r] = 0.f;
        }
#pragma unroll
        for (int ki = 0; ki < 4; ++ki)
#pragma unroll
            for (int r = 0; r < 4; ++r) {
                const float p = __expf(s[ki][r] - mx[r]);
                s[ki][r] = p;
                rs[r] += p;
            }
#pragma unroll
        for (int r = 0; r < 4; ++r) {
            float v = rs[r];
#pragma unroll
            for (int msk = 8; msk >= 1; msk >>= 1) v += __shfl_xor(v, msk, 64);
            l_r[r] = l_r[r] * alpha[r] + v;
            m_r[r] = mx[r];
        }
#pragma unroll
        for (int di = 0; di < 4; ++di)
#pragma unroll
            for (int r = 0; r < 4; ++r) O[di][r] *= alpha[r];

        unsigned short* Pw = Ps[w];
#pragma unroll
        for (int ki = 0; ki < 4; ++ki)
#pragma unroll
            for (int r = 0; r < 4; ++r)
                Pw[(quad * 4 + r) * LDP + 16 * ki + l15] = f2bf(s[ki][r]);

        const bf16x8 pf0 = *(const bf16x8*)(Pw + l15 * LDP + quad * 8);
        const bf16x8 pf1 = *(const bf16x8*)(Pw + l15 * LDP + 32 + quad * 8);
#pragma unroll
        for (int di = 0; di < 4; ++di) {
            const bf16x8 vf0 = *(const bf16x8*)(VTs + (16 * di + l15) * LDP + quad * 8);
            const bf16x8 vf1 = *(const bf16x8*)(VTs + (16 * di + l15) * LDP + 32 + quad * 8);
            O[di] = __builtin_amdgcn_mfma_f32_16x16x32_bf16(pf0, vf0, O[di], 0, 0, 0);
            O[di] = __builtin_amdgcn_mfma_f32_16x16x32_bf16(pf1, vf1, O[di], 0, 0, 0);
        }
    }

    const int pbase = ((b * 64 + qt) * 4 + ch) * 64;
    float* Op = Opart + (size_t)pbase * HH + 16 * w * HH;
#pragma unroll
    for (int di = 0; di < 4; ++di)
#pragma unroll
        for (int r = 0; r < 4; ++r)
            Op[(quad * 4 + r) * HH + 16 * di + l15] = O[di][r];
    if (l15 == 0) {
#pragma unroll
        for (int r = 0; r < 4; ++r) {
            const int prow = pbase + 16 * w + quad * 4 + r;
            ml[prow * 2]     = m_r[r];
            ml[prow * 2 + 1] = l_r[r];
        }
    }
}

// ------------- Kernel 2b: merge partials ------------------------------------
__global__ __launch_bounds__(256) void attn_merge(const float* __restrict__ Opart,
                                                  const float* __restrict__ ml,
                                                  float* __restrict__ out) {
    const int g = blockIdx.x * 256 + threadIdx.x;   // row*64 + d
    const int row = g >> 6, d = g & 63;
    const int b = row >> 12, t = row & (TT - 1);
    const int qt = t >> 6, rloc = t & 63;
    const int nchunk = (qt >> 4) + 1;
    const int pbase = ((b * 64 + qt) * 4) * 64 + rloc;

    float M = -INFINITY;
#pragma unroll 4
    for (int c = 0; c < nchunk; ++c) M = fmaxf(M, ml[(pbase + c * 64) * 2]);
    float O = 0.f, L = 0.f;
#pragma unroll 4
    for (int c = 0; c < nchunk; ++c) {
        const int idx = pbase + c * 64;
        const float wgt = __expf(ml[idx * 2] - M);
        L += wgt * ml[idx * 2 + 1];
        O += wgt * Opart[(size_t)idx * HH + d];
    }
    out[(size_t)row * HH + d] = O / L;
}

// ------------- Fallback: single-pass attention ------------------------------
__global__ __launch_bounds__(256) void attn_full(const unsigned short* __restrict__ qb,
                                                 const unsigned short* __restrict__ kb,
                                                 const unsigned short* __restrict__ vbt,
                                                 float* __restrict__ out) {
    __shared__ unsigned short Ks[64 * LDP];
    __shared__ unsigned short VTs[64 * LDP];
    __shared__ unsigned short Ps[4][16 * LDP];

    const int b   = blockIdx.x >> 6;
    const int qt  = blockIdx.x & 63;
    const int q0  = qt * 64;
    const int tid = threadIdx.x;
    const int w = tid >> 6, lane = tid & 63;
    const int l15 = lane & 15, quad = lane >> 4;

    const unsigned short* Qb  = qb  + (size_t)b * TT * HH;
    const unsigned short* Kb  = kb  + (size_t)b * TT * HH;
    const unsigned short* VTb = vbt + (size_t)b * HH * TT;

    const int qrow = q0 + 16 * w + l15;
    const bf16x8 qf0 = *(const bf16x8*)(Qb + (size_t)qrow * HH + quad * 8);
    const bf16x8 qf1 = *(const bf16x8*)(Qb + (size_t)qrow * HH + 32 + quad * 8);

    floatx4 O[4] = {};
    float m_r[4], l_r[4];
#pragma unroll
    for (int r = 0; r < 4; ++r) { m_r[r] = -INFINITY; l_r[r] = 0.f; }

    for (int kt = 0; kt <= qt; ++kt) {
        __syncthreads();
        const unsigned short* Kt = Kb + (size_t)(kt * 64) * HH;
        const unsigned short* Vt = VTb + kt * 64;
#pragma unroll
        for (int e = 0; e < 2; ++e) {
            const int chunk = tid + 256 * e;
            const int r = chunk >> 3, c0 = (chunk & 7) * 8;
            *(u16x8*)(Ks + r * LDP + c0)  = *(const u16x8*)(Kt + r * HH + c0);
            *(u16x8*)(VTs + r * LDP + c0) = *(const u16x8*)(Vt + (size_t)r * TT + c0);
        }
        __syncthreads();

        floatx4 s[4];
#pragma unroll
        for (int ki = 0; ki < 4; ++ki) {
            const bf16x8 kf0 = *(const bf16x8*)(Ks + (16 * ki + l15) * LDP + quad * 8);
            const bf16x8 kf1 = *(const bf16x8*)(Ks + (16 * ki + l15) * LDP + 32 + quad * 8);
            floatx4 c = {};
            c = __builtin_amdgcn_mfma_f32_16x16x32_bf16(qf0, kf0, c, 0, 0, 0);
            c = __builtin_amdgcn_mfma_f32_16x16x32_bf16(qf1, kf1, c, 0, 0, 0);
            s[ki] = c * 0.125f;
        }
        if (kt == qt) {
#pragma unroll
            for (int ki = 0; ki < 4; ++ki)
#pragma unroll
                for (int r = 0; r < 4; ++r)
                    if (16 * ki + l15 > 16 * w + quad * 4 + r) s[ki][r] = -INFINITY;
        }
        float mx[4], alpha[4], rs[4];
#pragma unroll
        for (int r = 0; r < 4; ++r) {
            float v = fmaxf(fmaxf(s[0][r], s[1][r]), fmaxf(s[2][r], s[3][r]));
#pragma unroll
            for (int msk = 8; msk >= 1; msk >>= 1) v = fmaxf(v, __shfl_xor(v, msk, 64));
            mx[r] = fmaxf(v, m_r[r]);
            alpha[r] = __expf(m_r[r] - mx[r]);
            rs[r] = 0.f;
        }
#pragma unroll
        for (int ki = 0; ki < 4; ++ki)
#pragma unroll
            for (int r = 0; r < 4; ++r) {
                const float p = __expf(s[ki][r] - mx[r]);
                s[ki][r] = p; rs[r] += p;
            }
#pragma unroll
        for (int r = 0; r < 4; ++r) {
            float v = rs[r];
#pragma unroll
            for (int msk = 8; msk >= 1; msk >>= 1) v += __shfl_xor(v, msk, 64);
            l_r[r] = l_r[r] * alpha[r] + v;
            m_r[r] = mx[r];
        }
#pragma unroll
        for (int di = 0; di < 4; ++di)
#pragma unroll
            for (int r = 0; r < 4; ++r) O[di][r] *= alpha[r];

        unsigned short* Pw = Ps[w];
#pragma unroll
        for (int ki = 0; ki < 4; ++ki)
#pragma unroll
            for (int r = 0; r < 4; ++r)
                Pw[(quad * 4 + r) * LDP + 16 * ki + l15] = f2bf(s[ki][r]);

        const bf16x8 pf0 = *(const bf16x8*)(Pw + l15 * LDP + quad * 8);
        const bf16x8 pf1 = *(const bf16x8*)(Pw + l15 * LDP + 32 + quad * 8);
#pragma unroll
        for (int di = 0; di < 4; ++di) {
            const bf16x8 vf0 = *(const bf16x8*)(VTs + (16 * di + l15) * LDP + quad * 8);
            const bf16x8 vf1 = *(const bf16x8*)(VTs + (16 * di + l15) * LDP + 32 + quad * 8);
            O[di] = __builtin_amdgcn_mfma_f32_16x16x32_bf16(pf0, vf0, O[di], 0, 0, 0);
            O[di] = __builtin_amdgcn_mfma_f32_16x16x32_bf16(pf1, vf1, O[di], 0, 0, 0);
        }
    }
    float* outp = out + ((size_t)b * TT + q0 + 16 * w) * HH;
#pragma unroll
    for (int di = 0; di < 4; ++di)
#pragma unroll
        for (int r = 0; r < 4; ++r)
            outp[(quad * 4 + r) * HH + 16 * di + l15] = O[di][r] / l_r[r];
}

extern "C" void kernel_launch(void* const* d_in, const int* in_sizes, int n_in,
                              void* d_out, int out_size, void* d_ws, size_t ws_size,
                              hipStream_t stream) {
    const float* x  = (const float*)d_in[0];
    const float* Wq = (const float*)d_in[1];
    const float* Wk = (const float*)d_in[2];
    const float* Wv = (const float*)d_in[3];
    float* out = (float*)d_out;

    const size_t nQKV = (size_t)BB * TT * HH;           // 1 Mi elems
    unsigned short* qb  = (unsigned short*)d_ws;
    unsigned short* kb  = qb + nQKV;
    unsigned short* vbt = kb + nQKV;
    unsigned short* wt  = vbt + nQKV;                   // NN*CC ushorts
    char* after_wt = (char*)(wt + (size_t)NN * CC);
    float* Opart = (float*)after_wt;                    // 256*4*64*64 floats = 16 MB
    float* ml    = Opart + (size_t)256 * 4 * 64 * HH;   // 256*4*64*2 floats = 512 KB
    const size_t need = (size_t)((char*)(ml + 256 * 4 * 64 * 2) - (char*)d_ws);

    wprep<<<(NN * CC + 255) / 256, 256, 0, stream>>>(Wq, Wk, Wv, wt);
    qkv_gemm<<<(BB * TT) / GR, 256, 0, stream>>>(x, wt, qb, kb, vbt);
    if (ws_size >= need) {
        attn_part<<<BB * 160, 256, 0, stream>>>(qb, kb, vbt, Opart, ml);
        attn_merge<<<(BB * TT * HH) / 256, 256, 0, stream>>>(Opart, ml, out);
    } else {
        attn_full<<<BB * (TT / 64), 256, 0, stream>>>(qb, kb, vbt, out);
    }
}